// Round 7
// baseline (163.343 us; speedup 1.0000x reference)
//
#include <hip/hip_runtime.h>

typedef unsigned short u16;
typedef __bf16 bf16x8 __attribute__((ext_vector_type(8)));
typedef float f32x4 __attribute__((ext_vector_type(4)));

#define WEMD 400
#define RANK 396
#define NA   16384     // SEQ*BATCH
#define KP   416       // padded wemd (400->416) for Ubt/Tbt rows
#define K2   448       // padded rank (396->448) for gemm_big K (7 chunks of 64)
#define BSTR 896       // byte stride of H and G rows (448*2)
#define NBC  2500
#define NBCP 2560

// ---- ws layout (bytes) ----
#define OFF_UBT  13658112u          // u16 [512][416]
#define OFF_TBT  14084096u          // u16 [512][416]
#define OFF_G    14689280u          // u16 [2560][448]
#define OFF_H    16983040u          // u16 [16384][448]

#define WBYTES_MAX 26214384ull      // 16384*400*4 - 16 (clamp for 16B tail reads)

__device__ __forceinline__ u16 f2bf(float f) {
  union { float f; unsigned u; } v; v.f = f;
  unsigned u = v.u;
  return (u16)((u + 0x7FFFu + ((u >> 16) & 1u)) >> 16);  // RNE
}

typedef __attribute__((address_space(3))) unsigned char lds_byte;
typedef __attribute__((address_space(1))) const unsigned char glob_byte;

__device__ __forceinline__ void gload16(const void* g, void* l) {
  __builtin_amdgcn_global_load_lds((glob_byte*)g, (lds_byte*)l, 16, 0, 0);
}

// ---------- prep: Ubt/Tbt transpose only ----------
__global__ void prep_ut(const float* __restrict__ U, const float* __restrict__ T,
                        u16* __restrict__ Ubt, u16* __restrict__ Tbt) {
  int idx = blockIdx.x * 256 + threadIdx.x;           // over 512*416
  if (idx >= 512 * KP) return;
  int n = idx / KP, k = idx - n * KP;
  u16 uo = 0, to = 0;
  if (n < RANK && k < WEMD) { uo = f2bf(U[(size_t)k * RANK + n]); to = f2bf(T[(size_t)k * RANK + n]); }
  Ubt[idx] = uo; Tbt[idx] = to;
}

// ---------- H = (word@U) * (neighbor@T), fp32-direct A staging ----------
// Blocks 0..511: GEMM (tm = (bid>>2)*128, tn = (bid&3)*128).
// Blocks 512..575: G-prep grid-stride loop (G needed only by gemm_big2).
// A tiles [128][128B fp32] staged swizzled (phys = logical ^ ((row&7)<<4),
// linear dest / inverse-swizzled source / swizzle on read). B tiles bf16
// [128][64B] linear (R6-proven layout). k in [400,416) reads garbage floats
// (next row) but B rows are zero there -> contributes 0.
__global__ __launch_bounds__(256) void gemm_h2(
    const float* __restrict__ word, const float* __restrict__ first,
    const u16* __restrict__ Ubt, const u16* __restrict__ Tbt,
    u16* __restrict__ H,
    const float* __restrict__ tag, const float* __restrict__ V,
    const float* __restrict__ Wm, u16* __restrict__ G) {
  if (blockIdx.x >= 512) {                      // ---- G-prep tail blocks ----
    for (int j = (blockIdx.x - 512) * 256 + threadIdx.x; j < NBCP * K2; j += 64 * 256) {
      int bc = j / K2, k = j - bc * K2;
      u16 g = 0;
      if (bc < NBC && k < RANK) {
        int b = bc / 50, c = bc - b * 50;
        float a2 = 0.f, a3 = 0.f;
        #pragma unroll
        for (int e = 0; e < 20; ++e) {
          a2 += tag[b * 20 + e] * V[e * RANK + k];
          a3 += tag[c * 20 + e] * Wm[e * RANK + k];
        }
        g = f2bf(a2 * a3);
      }
      G[(size_t)bc * K2 + k] = g;
    }
    return;
  }

  __shared__ __align__(16) char ldsb[49152];    // Aw 16K | An 16K | Bu 8K | Bt 8K
  char* ldsAw = ldsb;
  char* ldsAn = ldsb + 16384;
  const u16* Bu = (const u16*)(ldsb + 32768);
  const u16* Bt = (const u16*)(ldsb + 40960);

  const int tid = threadIdx.x;
  const int l = tid & 63, w = tid >> 6;
  const int wm = w >> 1, wn = w & 1;
  const int tm = (blockIdx.x >> 2) * 128, tn = (blockIdx.x & 3) * 128;

  f32x4 acc0[4][4] = {}, acc1[4][4] = {};
  const int fo_b = (wn * 64 + (l & 15)) * 32 + (l >> 4) * 8;   // u16 units

  for (int kt = 0; kt < 13; ++kt) {
    const int kb4 = kt * 128;                   // fp32 bytes for 32 k-values
    const int kb  = kt * 64;                    // bf16 bytes
    #pragma unroll
    for (int q = 0; q < 4; ++q) {
      int P = tid * 16 + q * 4096;
      int row = P >> 7, colp = P & 127;
      int col = colp ^ ((row & 7) << 4);
      size_t offw = (size_t)(tm + row) * 1600 + kb4 + col;
      if (offw > WBYTES_MAX) offw = WBYTES_MAX;
      gload16((const char*)word + offw, ldsAw + P);
      const char* srcn;
      if (tm + row >= 32) {
        size_t offn = (size_t)(tm + row - 32) * 1600 + kb4 + col;
        if (offn > WBYTES_MAX) offn = WBYTES_MAX;
        srcn = (const char*)word + offn;
      } else {
        int offf = kb4 + col; if (offf > 1584) offf = 1584;
        srcn = (const char*)first + offf;
      }
      gload16(srcn, ldsAn + P);
    }
    #pragma unroll
    for (int q = 0; q < 2; ++q) {
      int P = tid * 16 + q * 4096;
      int row = P >> 6, colb = P & 63;
      gload16((const char*)Ubt + (size_t)(tn + row) * 832 + kb + colb, (char*)Bu + P);
      gload16((const char*)Tbt + (size_t)(tn + row) * 832 + kb + colb, (char*)Bt + P);
    }
    __syncthreads();

    bf16x8 a0[4], a1[4], bu[4], bt[4];
    #pragma unroll
    for (int i = 0; i < 4; ++i) {
      const int ar = wm * 64 + i * 16 + (l & 15);
      const int swz = (ar & 7) << 4;
      const int c0 = (l >> 4) * 32;
      f32x4 w0 = *(const f32x4*)(ldsAw + ar * 128 + (c0 ^ swz));
      f32x4 w1 = *(const f32x4*)(ldsAw + ar * 128 + ((c0 + 16) ^ swz));
      f32x4 n0 = *(const f32x4*)(ldsAn + ar * 128 + (c0 ^ swz));
      f32x4 n1 = *(const f32x4*)(ldsAn + ar * 128 + ((c0 + 16) ^ swz));
      bf16x8 aw, an;
      #pragma unroll
      for (int jj = 0; jj < 4; ++jj) {
        aw[jj] = (__bf16)w0[jj]; aw[4 + jj] = (__bf16)w1[jj];
        an[jj] = (__bf16)n0[jj]; an[4 + jj] = (__bf16)n1[jj];
      }
      a0[i] = aw; a1[i] = an;
      bu[i] = *(const bf16x8*)(Bu + fo_b + i * 16 * 32);
      bt[i] = *(const bf16x8*)(Bt + fo_b + i * 16 * 32);
    }
    #pragma unroll
    for (int i = 0; i < 4; ++i)
      #pragma unroll
      for (int j = 0; j < 4; ++j) {
        acc0[i][j] = __builtin_amdgcn_mfma_f32_16x16x32_bf16(a0[i], bu[j], acc0[i][j], 0, 0, 0);
        acc1[i][j] = __builtin_amdgcn_mfma_f32_16x16x32_bf16(a1[i], bt[j], acc1[i][j], 0, 0, 0);
      }
    __syncthreads();
  }

  const int r4 = (l >> 4) * 4, cc = l & 15;
  #pragma unroll
  for (int i = 0; i < 4; ++i)
    #pragma unroll
    for (int j = 0; j < 4; ++j) {
      const int col = tn + wn * 64 + j * 16 + cc;
      if (col < K2) {
        #pragma unroll
        for (int r = 0; r < 4; ++r) {
          const int rowg = tm + wm * 64 + i * 16 + r4 + r;
          H[(size_t)rowg * K2 + col] = f2bf(acc0[i][j][r] * acc1[i][j][r]);
        }
      }
    }
}

// ---------- out[16384,2500] = H[.,448] @ G^T (R4-proven best) ----------
// 128x128 tile, BK=64, 256 thr (4 waves 2x2), single-buffered 32 KiB LDS ->
// 3 blocks/CU; co-residency provides the overlap (m114). Validated swizzle.
__global__ __launch_bounds__(256, 3) void gemm_big2(const u16* __restrict__ H,
                                                    const u16* __restrict__ G,
                                                    float* __restrict__ out) {
  __shared__ u16 lds[2 * 8192];   // A 16 KiB + B 16 KiB
  char* ldsb = (char*)lds;
  const int tid = threadIdx.x;
  const int lane = tid & 63, wid = tid >> 6;
  const int wm = wid >> 1, wn = wid & 1;

  int bs = (int)blockIdx.x;
  bs = (bs & 7) * 320 + (bs >> 3);              // XCD swizzle, 2560 % 8 == 0
  const int tm = (bs / 20) * 128, tn = (bs % 20) * 128;

  const char* gH = (const char*)H + (size_t)tm * BSTR;
  const char* gG = (const char*)G + (size_t)tn * BSTR;

  int sP[4], sR[4], sC[4];
  #pragma unroll
  for (int q = 0; q < 4; ++q) {
    int P = tid * 16 + q * 4096;
    int L = P ^ (((P >> 7) & 7) << 4);
    sP[q] = P; sR[q] = L >> 7; sC[q] = L & 127;
  }
  const int arow = (lane & 15) * 128;
  const int sw = (lane & 7) << 4;

  f32x4 acc[4][4] = {};

  for (int kt = 0; kt < 7; ++kt) {
    const int kb = kt * 128;
    #pragma unroll
    for (int q = 0; q < 4; ++q) {
      gload16(gH + (size_t)sR[q] * BSTR + kb + sC[q], ldsb + sP[q]);
      gload16(gG + (size_t)sR[q] * BSTR + kb + sC[q], ldsb + 16384 + sP[q]);
    }
    __syncthreads();
    #pragma unroll
    for (int ks = 0; ks < 2; ++ks) {
      const int csw = (ks * 64 + (lane >> 4) * 16) ^ sw;
      bf16x8 a[4], b[4];
      #pragma unroll
      for (int rf = 0; rf < 4; ++rf)
        a[rf] = *(const bf16x8*)(ldsb + wm * 8192 + rf * 2048 + arow + csw);
      #pragma unroll
      for (int cf = 0; cf < 4; ++cf)
        b[cf] = *(const bf16x8*)(ldsb + 16384 + wn * 8192 + cf * 2048 + arow + csw);
      #pragma unroll
      for (int rf = 0; rf < 4; ++rf)
        #pragma unroll
        for (int cf = 0; cf < 4; ++cf)
          acc[rf][cf] = __builtin_amdgcn_mfma_f32_16x16x32_bf16(a[rf], b[cf], acc[rf][cf], 0, 0, 0);
    }
    __syncthreads();
  }

  const int r4 = (lane >> 4) * 4, cc = lane & 15;
  const int rbase = tm + wm * 64 + r4;
  const int cbase = tn + wn * 64 + cc;
  #pragma unroll
  for (int rf = 0; rf < 4; ++rf)
    #pragma unroll
    for (int cf = 0; cf < 4; ++cf) {
      const int col = cbase + cf * 16;
      if (col < NBC) {
        #pragma unroll
        for (int rr = 0; rr < 4; ++rr)
          out[(size_t)(rbase + rf * 16 + rr) * NBC + col] = acc[rf][cf][rr];
      }
    }
}

extern "C" void kernel_launch(void* const* d_in, const int* in_sizes, int n_in,
                              void* d_out, int out_size, void* d_ws, size_t ws_size,
                              hipStream_t stream) {
  const float* word  = (const float*)d_in[0];
  const float* tag   = (const float*)d_in[1];
  const float* Tm    = (const float*)d_in[2];
  const float* Um    = (const float*)d_in[3];
  const float* Vm    = (const float*)d_in[4];
  const float* Wm    = (const float*)d_in[5];
  const float* first = (const float*)d_in[6];
  float* out = (float*)d_out;
  char* ws = (char*)d_ws;

  u16*   Ubt = (u16*)(ws + OFF_UBT);
  u16*   Tbt = (u16*)(ws + OFF_TBT);
  u16*   G   = (u16*)(ws + OFF_G);
  u16*   H   = (u16*)(ws + OFF_H);

  hipLaunchKernelGGL(prep_ut,  dim3((512 * KP + 255) / 256), dim3(256), 0, stream, Um, Tm, Ubt, Tbt);
  hipLaunchKernelGGL(gemm_h2,  dim3(576), dim3(256), 0, stream,
                     word, first, Ubt, Tbt, H, tag, Vm, Wm, G);
  hipLaunchKernelGGL(gemm_big2, dim3(2560), dim3(256), 0, stream, H, G, out);
}

// Round 8
// 154.444 us; speedup vs baseline: 1.0576x; 1.0576x over previous
//
#include <hip/hip_runtime.h>

typedef unsigned short u16;
typedef __bf16 bf16x8 __attribute__((ext_vector_type(8)));
typedef float f32x4 __attribute__((ext_vector_type(4)));

#define WEMD 400
#define RANK 396
#define NA   16384     // SEQ*BATCH
#define KP   416       // padded wemd (400->416) for gemm_h K
#define K2   448       // padded rank (396->448) for gemm_big K (7 tiles of 64)
#define BSTR 896       // byte stride of H and G rows (448*2)
#define NBC  2500
#define NBCP 2560

// ---- ws layout (bytes) ----
#define OFF_WBF  0u                 // u16 [16416][416]
#define OFF_UBT  13658112u          // u16 [512][416]
#define OFF_TBT  14084096u          // u16 [512][416]
#define OFF_G    14689280u          // u16 [2560][448]
#define OFF_H    16983040u          // u16 [16384][448]

__device__ __forceinline__ u16 f2bf(float f) {
  union { float f; unsigned u; } v; v.f = f;
  unsigned u = v.u;
  return (u16)((u + 0x7FFFu + ((u >> 16) & 1u)) >> 16);  // RNE
}

typedef __attribute__((address_space(3))) unsigned char lds_byte;
typedef __attribute__((address_space(1))) const unsigned char glob_byte;

__device__ __forceinline__ void gload16(const void* g, void* l) {
  __builtin_amdgcn_global_load_lds((glob_byte*)g, (lds_byte*)l, 16, 0, 0);
}

#define FENCE() asm volatile("" ::: "memory")
#define BARRIER() do { FENCE(); __builtin_amdgcn_s_barrier(); FENCE(); } while (0)
#define VMCNT0() asm volatile("s_waitcnt vmcnt(0)" ::: "memory")

// ---------- fused prep: Wbf + Ubt/Tbt + G (R4-proven) ----------
__global__ __launch_bounds__(256) void prep_all(
    const float* __restrict__ word, const float* __restrict__ first,
    const float* __restrict__ U, const float* __restrict__ T,
    const float* __restrict__ tag, const float* __restrict__ V,
    const float* __restrict__ W,
    u16* __restrict__ Wbf, u16* __restrict__ Ubt, u16* __restrict__ Tbt,
    u16* __restrict__ G) {
  const int R0 = 16416 * 104;          // Wbf as float4 items (416/4 = 104 per row)
  const int R1 = 416 << 9;             // U/T transpose
  const int R2 = NBCP * K2;            // G items
  const int total = R0 + R1 + R2;
  for (int i = blockIdx.x * 256 + threadIdx.x; i < total; i += gridDim.x * 256) {
    if (i < R0) {
      int r = i / 104, c4 = i - r * 104;
      ushort4 o = {0, 0, 0, 0};
      if (c4 < 100) {
        const float* src = (r < 32) ? (first + c4 * 4)
                                    : (word + (size_t)(r - 32) * WEMD + c4 * 4);
        float4 v = *(const float4*)src;
        o.x = f2bf(v.x); o.y = f2bf(v.y); o.z = f2bf(v.z); o.w = f2bf(v.w);
      }
      *(ushort4*)(Wbf + (size_t)r * KP + c4 * 4) = o;
    } else if (i < R0 + R1) {
      int j = i - R0;
      int n = j & 511, k = j >> 9;
      u16 uo = 0, to = 0;
      if (n < RANK && k < WEMD) {
        uo = f2bf(U[(size_t)k * RANK + n]);
        to = f2bf(T[(size_t)k * RANK + n]);
      }
      Ubt[(size_t)n * KP + k] = uo;
      Tbt[(size_t)n * KP + k] = to;
    } else {
      int j = i - R0 - R1;
      int bc = j / K2, k = j - bc * K2;
      u16 g = 0;
      if (bc < NBC && k < RANK) {
        int b = bc / 50, c = bc - b * 50;
        float a2 = 0.f, a3 = 0.f;
        #pragma unroll
        for (int e = 0; e < 20; ++e) {
          a2 += tag[b * 20 + e] * V[e * RANK + k];
          a3 += tag[c * 20 + e] * W[e * RANK + k];
        }
        g = f2bf(a2 * a3);
      }
      G[(size_t)bc * K2 + k] = g;
    }
  }
}

// ---------- H = (word@U) * (neighbor@T), bf16 out, stride 448 (R4-proven) ----------
__global__ __launch_bounds__(256) void gemm_h(const u16* __restrict__ Wbf,
                                              const u16* __restrict__ Ubt,
                                              const u16* __restrict__ Tbt,
                                              u16* __restrict__ H) {
  __shared__ u16 As0[128 * 32], As1[128 * 32], Bu[128 * 32], Bt[128 * 32];
  const int tid = threadIdx.x;
  const int l = tid & 63, w = tid >> 6;
  const int wm = w >> 1, wn = w & 1;
  const int tm = (blockIdx.x >> 2) * 128, tn = (blockIdx.x & 3) * 128;

  f32x4 acc0[4][4] = {}, acc1[4][4] = {};

  const int srow = tid >> 2;
  const int scolb = (tid & 3) * 16;
  const char* gA0 = (const char*)Wbf + (size_t)(tm + 32 + srow) * 832 + scolb;
  const char* gA1 = (const char*)Wbf + (size_t)(tm + srow) * 832 + scolb;
  const char* gU  = (const char*)Ubt + (size_t)(tn + srow) * 832 + scolb;
  const char* gT  = (const char*)Tbt + (size_t)(tn + srow) * 832 + scolb;
  char* lA0 = (char*)As0 + tid * 16;
  char* lA1 = (char*)As1 + tid * 16;
  char* lU  = (char*)Bu  + tid * 16;
  char* lT  = (char*)Bt  + tid * 16;

  const int fo_a = (wm * 64 + (l & 15)) * 32 + (l >> 4) * 8;
  const int fo_b = (wn * 64 + (l & 15)) * 32 + (l >> 4) * 8;

  for (int kt = 0; kt < 13; ++kt) {
    const int kb = kt * 64;
    gload16(gA0 + kb, lA0); gload16(gA0 + kb + (size_t)64 * 832, lA0 + 4096);
    gload16(gA1 + kb, lA1); gload16(gA1 + kb + (size_t)64 * 832, lA1 + 4096);
    gload16(gU  + kb, lU ); gload16(gU  + kb + (size_t)64 * 832, lU  + 4096);
    gload16(gT  + kb, lT ); gload16(gT  + kb + (size_t)64 * 832, lT  + 4096);
    __syncthreads();
    bf16x8 a0[4], a1[4], bu[4], bt[4];
    #pragma unroll
    for (int i = 0; i < 4; ++i) {
      a0[i] = *(const bf16x8*)(As0 + fo_a + i * 16 * 32);
      a1[i] = *(const bf16x8*)(As1 + fo_a + i * 16 * 32);
      bu[i] = *(const bf16x8*)(Bu  + fo_b + i * 16 * 32);
      bt[i] = *(const bf16x8*)(Bt  + fo_b + i * 16 * 32);
    }
    #pragma unroll
    for (int i = 0; i < 4; ++i)
      #pragma unroll
      for (int j = 0; j < 4; ++j) {
        acc0[i][j] = __builtin_amdgcn_mfma_f32_16x16x32_bf16(a0[i], bu[j], acc0[i][j], 0, 0, 0);
        acc1[i][j] = __builtin_amdgcn_mfma_f32_16x16x32_bf16(a1[i], bt[j], acc1[i][j], 0, 0, 0);
      }
    __syncthreads();
  }

  const int r4 = (l >> 4) * 4, cc = l & 15;
  #pragma unroll
  for (int i = 0; i < 4; ++i)
    #pragma unroll
    for (int j = 0; j < 4; ++j) {
      const int col = tn + wn * 64 + j * 16 + cc;
      if (col < K2) {
        #pragma unroll
        for (int r = 0; r < 4; ++r) {
          const int rowg = tm + wm * 64 + i * 16 + r4 + r;
          H[(size_t)rowg * K2 + col] = f2bf(acc0[i][j][r] * acc1[i][j][r]);
        }
      }
    }
}

// ---------- out[16384,2500] = H[.,448] @ G^T : A-dbuf LDS + B-direct-L2 ----------
// 128x128 tile, BK=64, 256 thr (4 waves 2x2). A double-buffered in LDS
// (2 x 16 KiB = 32 KiB total, same as R4 -> 3 blocks/CU kept). B fragments
// loaded straight from G (L2-resident, 2.3 MB) into registers, prefetched one
// K-step ahead so the loads fly under the MFMAs. Halves the barrier-coupled
// staging volume; per-kt drain covers 16 KB instead of 32 KB.
// A swizzle (validated): physical = logical ^ ((row&7)<<4), both sides.
__global__ __launch_bounds__(256, 3) void gemm_big3(const u16* __restrict__ H,
                                                    const u16* __restrict__ G,
                                                    float* __restrict__ out) {
  __shared__ u16 lds[2 * 8192];   // A dbuf: 2 x 16 KiB
  char* ldsb = (char*)lds;
  const int tid = threadIdx.x;
  const int lane = tid & 63, wid = tid >> 6;
  const int wm = wid >> 1, wn = wid & 1;

  int bs = (int)blockIdx.x;
  bs = (bs & 7) * 320 + (bs >> 3);              // XCD swizzle, 2560 % 8 == 0
  const int tm = (bs / 20) * 128, tn = (bs % 20) * 128;

  const char* gH = (const char*)H + (size_t)tm * BSTR;

  // A stage addressing: 4 x 16B per thread per 16KB buffer
  int sP[4], sR[4], sC[4];
  #pragma unroll
  for (int q = 0; q < 4; ++q) {
    int P = tid * 16 + q * 4096;
    int L = P ^ (((P >> 7) & 7) << 4);
    sP[q] = P; sR[q] = L >> 7; sC[q] = L & 127;
  }
  const int arow = (lane & 15) * 128;
  const int sw = (lane & 7) << 4;

  // B-direct base pointers: frag (cf, ks) at row tn + wn*64 + cf*16 + (l&15),
  // byte col = kt*128 + ks*64 + (l>>4)*16
  const char* gBbase[4];
  #pragma unroll
  for (int cf = 0; cf < 4; ++cf)
    gBbase[cf] = (const char*)G +
                 (size_t)(tn + wn * 64 + cf * 16 + (lane & 15)) * BSTR +
                 (lane >> 4) * 16;

  f32x4 acc[4][4] = {};
  bf16x8 bc[2][4], bn[2][4];

  // prologue: stage A(0) -> buf0, load B(0)
  #pragma unroll
  for (int q = 0; q < 4; ++q)
    gload16(gH + (size_t)sR[q] * BSTR + sC[q], ldsb + sP[q]);
  #pragma unroll
  for (int ks = 0; ks < 2; ++ks)
    #pragma unroll
    for (int cf = 0; cf < 4; ++cf)
      bc[ks][cf] = *(const bf16x8*)(gBbase[cf] + ks * 64);
  VMCNT0();
  BARRIER();

  #pragma unroll
  for (int kt = 0; kt < 7; ++kt) {
    char* cbuf = ldsb + (kt & 1) * 16384;

    if (kt < 6) {                               // issue next A-stage + B-loads
      char* nbuf = ldsb + ((kt & 1) ^ 1) * 16384;
      const int kb = (kt + 1) * 128;
      #pragma unroll
      for (int q = 0; q < 4; ++q)
        gload16(gH + (size_t)sR[q] * BSTR + kb + sC[q], nbuf + sP[q]);
      #pragma unroll
      for (int ks = 0; ks < 2; ++ks)
        #pragma unroll
        for (int cf = 0; cf < 4; ++cf)
          bn[ks][cf] = *(const bf16x8*)(gBbase[cf] + kb + ks * 64);
    }

    #pragma unroll
    for (int ks = 0; ks < 2; ++ks) {
      const int csw = (ks * 64 + (lane >> 4) * 16) ^ sw;
      bf16x8 a[4];
      #pragma unroll
      for (int rf = 0; rf < 4; ++rf)
        a[rf] = *(const bf16x8*)(cbuf + wm * 8192 + rf * 2048 + arow + csw);
      #pragma unroll
      for (int rf = 0; rf < 4; ++rf)
        #pragma unroll
        for (int cf = 0; cf < 4; ++cf)
          acc[rf][cf] = __builtin_amdgcn_mfma_f32_16x16x32_bf16(a[rf], bc[ks][cf], acc[rf][cf], 0, 0, 0);
    }

    if (kt < 6) {
      BARRIER();                                // all waves done reading cbuf
      VMCNT0();                                 // A(kt+1) in LDS, B(kt+1) in regs
      #pragma unroll
      for (int ks = 0; ks < 2; ++ks)
        #pragma unroll
        for (int cf = 0; cf < 4; ++cf)
          bc[ks][cf] = bn[ks][cf];
    }
  }

  const int r4 = (lane >> 4) * 4, cc = lane & 15;
  const int rbase = tm + wm * 64 + r4;
  const int cbase = tn + wn * 64 + cc;
  #pragma unroll
  for (int rf = 0; rf < 4; ++rf)
    #pragma unroll
    for (int cf = 0; cf < 4; ++cf) {
      const int col = cbase + cf * 16;
      if (col < NBC) {
        #pragma unroll
        for (int rr = 0; rr < 4; ++rr)
          out[(size_t)(rbase + rf * 16 + rr) * NBC + col] = acc[rf][cf][rr];
      }
    }
}

extern "C" void kernel_launch(void* const* d_in, const int* in_sizes, int n_in,
                              void* d_out, int out_size, void* d_ws, size_t ws_size,
                              hipStream_t stream) {
  const float* word  = (const float*)d_in[0];
  const float* tag   = (const float*)d_in[1];
  const float* Tm    = (const float*)d_in[2];
  const float* Um    = (const float*)d_in[3];
  const float* Vm    = (const float*)d_in[4];
  const float* Wm    = (const float*)d_in[5];
  const float* first = (const float*)d_in[6];
  float* out = (float*)d_out;
  char* ws = (char*)d_ws;

  u16*   Wbf = (u16*)(ws + OFF_WBF);
  u16*   Ubt = (u16*)(ws + OFF_UBT);
  u16*   Tbt = (u16*)(ws + OFF_TBT);
  u16*   G   = (u16*)(ws + OFF_G);
  u16*   H   = (u16*)(ws + OFF_H);

  hipLaunchKernelGGL(prep_all, dim3(2048), dim3(256), 0, stream,
                     word, first, Um, Tm, tag, Vm, Wm, Wbf, Ubt, Tbt, G);
  hipLaunchKernelGGL(gemm_h,   dim3(128 * 4), dim3(256), 0, stream, Wbf, Ubt, Tbt, H);
  hipLaunchKernelGGL(gemm_big3, dim3(2560), dim3(256), 0, stream, H, G, out);
}

// Round 10
// 123.012 us; speedup vs baseline: 1.3279x; 1.2555x over previous
//
#include <hip/hip_runtime.h>

typedef unsigned short u16;
typedef __bf16 bf16x8 __attribute__((ext_vector_type(8)));
typedef float f32x4 __attribute__((ext_vector_type(4)));

#define WEMD 400
#define RANK 396
#define NA   16384     // SEQ*BATCH
#define KP   416       // padded wemd (400->416) for gemm_h K
#define K2   448       // padded rank (396->448) for gemm_big K
#define BSTR 896       // byte stride of H and G rows (448*2)
#define NBC  2500
#define NBCP 2560

// ---- ws layout (bytes) ----
#define OFF_WBF  0u                 // u16 [16416][416]
#define OFF_UBT  13658112u          // u16 [512][416]
#define OFF_TBT  14084096u          // u16 [512][416]
#define OFF_G    14689280u          // u16 [2560][448]
#define OFF_H    16983040u          // u16 [16384][448]

__device__ __forceinline__ u16 f2bf(float f) {
  union { float f; unsigned u; } v; v.f = f;
  unsigned u = v.u;
  return (u16)((u + 0x7FFFu + ((u >> 16) & 1u)) >> 16);  // RNE
}

typedef __attribute__((address_space(3))) unsigned char lds_byte;
typedef __attribute__((address_space(1))) const unsigned char glob_byte;

__device__ __forceinline__ void gload16(const void* g, void* l) {
  __builtin_amdgcn_global_load_lds((glob_byte*)g, (lds_byte*)l, 16, 0, 0);
}

#define FENCE() asm volatile("" ::: "memory")
#define BARRIER() do { FENCE(); __builtin_amdgcn_s_barrier(); FENCE(); } while (0)
#define VMCNT0() asm volatile("s_waitcnt vmcnt(0)" ::: "memory")
#define VMCNT4() asm volatile("s_waitcnt vmcnt(4)" ::: "memory")

// ---------- fused prep: Wbf + Ubt/Tbt + G (R4-proven) ----------
__global__ __launch_bounds__(256) void prep_all(
    const float* __restrict__ word, const float* __restrict__ first,
    const float* __restrict__ U, const float* __restrict__ T,
    const float* __restrict__ tag, const float* __restrict__ V,
    const float* __restrict__ W,
    u16* __restrict__ Wbf, u16* __restrict__ Ubt, u16* __restrict__ Tbt,
    u16* __restrict__ G) {
  const int R0 = 16416 * 104;          // Wbf as float4 items (416/4 = 104 per row)
  const int R1 = 416 << 9;             // U/T transpose
  const int R2 = NBCP * K2;            // G items
  const int total = R0 + R1 + R2;
  for (int i = blockIdx.x * 256 + threadIdx.x; i < total; i += gridDim.x * 256) {
    if (i < R0) {
      int r = i / 104, c4 = i - r * 104;
      ushort4 o = {0, 0, 0, 0};
      if (c4 < 100) {
        const float* src = (r < 32) ? (first + c4 * 4)
                                    : (word + (size_t)(r - 32) * WEMD + c4 * 4);
        float4 v = *(const float4*)src;
        o.x = f2bf(v.x); o.y = f2bf(v.y); o.z = f2bf(v.z); o.w = f2bf(v.w);
      }
      *(ushort4*)(Wbf + (size_t)r * KP + c4 * 4) = o;
    } else if (i < R0 + R1) {
      int j = i - R0;
      int n = j & 511, k = j >> 9;
      u16 uo = 0, to = 0;
      if (n < RANK && k < WEMD) {
        uo = f2bf(U[(size_t)k * RANK + n]);
        to = f2bf(T[(size_t)k * RANK + n]);
      }
      Ubt[(size_t)n * KP + k] = uo;
      Tbt[(size_t)n * KP + k] = to;
    } else {
      int j = i - R0 - R1;
      int bc = j / K2, k = j - bc * K2;
      u16 g = 0;
      if (bc < NBC && k < RANK) {
        int b = bc / 50, c = bc - b * 50;
        float a2 = 0.f, a3 = 0.f;
        #pragma unroll
        for (int e = 0; e < 20; ++e) {
          a2 += tag[b * 20 + e] * V[e * RANK + k];
          a3 += tag[c * 20 + e] * W[e * RANK + k];
        }
        g = f2bf(a2 * a3);
      }
      G[(size_t)bc * K2 + k] = g;
    }
  }
}

// ---------- H = (word@U) * (neighbor@T), bf16 out, stride 448 (R4-proven) ----------
__global__ __launch_bounds__(256) void gemm_h(const u16* __restrict__ Wbf,
                                              const u16* __restrict__ Ubt,
                                              const u16* __restrict__ Tbt,
                                              u16* __restrict__ H) {
  __shared__ u16 As0[128 * 32], As1[128 * 32], Bu[128 * 32], Bt[128 * 32];
  const int tid = threadIdx.x;
  const int l = tid & 63, w = tid >> 6;
  const int wm = w >> 1, wn = w & 1;
  const int tm = (blockIdx.x >> 2) * 128, tn = (blockIdx.x & 3) * 128;

  f32x4 acc0[4][4] = {}, acc1[4][4] = {};

  const int srow = tid >> 2;
  const int scolb = (tid & 3) * 16;
  const char* gA0 = (const char*)Wbf + (size_t)(tm + 32 + srow) * 832 + scolb;
  const char* gA1 = (const char*)Wbf + (size_t)(tm + srow) * 832 + scolb;
  const char* gU  = (const char*)Ubt + (size_t)(tn + srow) * 832 + scolb;
  const char* gT  = (const char*)Tbt + (size_t)(tn + srow) * 832 + scolb;
  char* lA0 = (char*)As0 + tid * 16;
  char* lA1 = (char*)As1 + tid * 16;
  char* lU  = (char*)Bu  + tid * 16;
  char* lT  = (char*)Bt  + tid * 16;

  const int fo_a = (wm * 64 + (l & 15)) * 32 + (l >> 4) * 8;
  const int fo_b = (wn * 64 + (l & 15)) * 32 + (l >> 4) * 8;

  for (int kt = 0; kt < 13; ++kt) {
    const int kb = kt * 64;
    gload16(gA0 + kb, lA0); gload16(gA0 + kb + (size_t)64 * 832, lA0 + 4096);
    gload16(gA1 + kb, lA1); gload16(gA1 + kb + (size_t)64 * 832, lA1 + 4096);
    gload16(gU  + kb, lU ); gload16(gU  + kb + (size_t)64 * 832, lU  + 4096);
    gload16(gT  + kb, lT ); gload16(gT  + kb + (size_t)64 * 832, lT  + 4096);
    __syncthreads();
    bf16x8 a0[4], a1[4], bu[4], bt[4];
    #pragma unroll
    for (int i = 0; i < 4; ++i) {
      a0[i] = *(const bf16x8*)(As0 + fo_a + i * 16 * 32);
      a1[i] = *(const bf16x8*)(As1 + fo_a + i * 16 * 32);
      bu[i] = *(const bf16x8*)(Bu  + fo_b + i * 16 * 32);
      bt[i] = *(const bf16x8*)(Bt  + fo_b + i * 16 * 32);
    }
    #pragma unroll
    for (int i = 0; i < 4; ++i)
      #pragma unroll
      for (int j = 0; j < 4; ++j) {
        acc0[i][j] = __builtin_amdgcn_mfma_f32_16x16x32_bf16(a0[i], bu[j], acc0[i][j], 0, 0, 0);
        acc1[i][j] = __builtin_amdgcn_mfma_f32_16x16x32_bf16(a1[i], bt[j], acc1[i][j], 0, 0, 0);
      }
    __syncthreads();
  }

  const int r4 = (l >> 4) * 4, cc = l & 15;
  #pragma unroll
  for (int i = 0; i < 4; ++i)
    #pragma unroll
    for (int j = 0; j < 4; ++j) {
      const int col = tn + wn * 64 + j * 16 + cc;
      if (col < K2) {
        #pragma unroll
        for (int r = 0; r < 4; ++r) {
          const int rowg = tm + wm * 64 + i * 16 + r4 + r;
          H[(size_t)rowg * K2 + col] = f2bf(acc0[i][j][r] * acc1[i][j][r]);
        }
      }
    }
}

// ---------- out[16384,2500] = H[.,448] @ G^T : ring-3, RACE-FIXED ----------
// 128x128 tile, 256 thr (4 waves 2x2). K = 14 half-quanta of 32k; region =
// A-half 8KB + B-half 8KB = 16KB; ring of 3 (48 KB -> 3 blocks/CU).
// CORRECT wait order (R2/m201 pattern): vmcnt(4) [retire own quantum j,
// quantum j+1 stays in flight] -> s_barrier [all threads' quantum j landed]
// -> issue quantum j+2 into region (j+2)%3 [distinct from read j%3 and
// in-flight (j+1)%3; its readers (iter j-1) all passed this barrier]
// -> ds_read + 16 MFMA. Never drains to 0 until the tail.
// Swizzle: phys_col = logical_col ^ (((row>>1)&3)<<4); inverse-swizzled
// global source, linear LDS dest, swizzled read (rule 21).
__global__ __launch_bounds__(256, 3) void gemm_big4(const u16* __restrict__ H,
                                                    const u16* __restrict__ G,
                                                    float* __restrict__ out) {
  __shared__ u16 lds[3 * 8192];   // 3 x (A 8KB + B 8KB) = 48 KB
  char* ldsb = (char*)lds;
  const int tid = threadIdx.x;
  const int lane = tid & 63, wid = tid >> 6;
  const int wm = wid >> 1, wn = wid & 1;

  int bs = (int)blockIdx.x;
  bs = (bs & 7) * 320 + (bs >> 3);              // XCD swizzle, 2560 % 8 == 0
  const int tm = (bs / 20) * 128, tn = (bs % 20) * 128;

  const char* gHb = (const char*)H;
  const char* gGb = (const char*)G;

  // stage addressing: 2 x 16B per thread per operand half
  int aP[2], bP[2];
  long aOff[2], bOff[2];
  #pragma unroll
  for (int q = 0; q < 2; ++q) {
    int P = tid * 16 + q * 4096;                // [0, 8192)
    int row = P >> 6;
    int lcol = (P & 63) ^ (((row >> 1) & 3) << 4);
    aP[q] = P;        aOff[q] = (long)(tm + row) * BSTR + lcol;
    bP[q] = 8192 + P; bOff[q] = (long)(tn + row) * BSTR + lcol;
  }

  // fragment read offsets (swizzled)
  int aro[4], bro[4];
  #pragma unroll
  for (int f = 0; f < 4; ++f) {
    int ra = wm * 64 + f * 16 + (lane & 15);
    int rb = wn * 64 + f * 16 + (lane & 15);
    aro[f] = ra * 64 + (((lane >> 4) * 16) ^ (((ra >> 1) & 3) << 4));
    bro[f] = rb * 64 + (((lane >> 4) * 16) ^ (((rb >> 1) & 3) << 4));
  }

  f32x4 acc[4][4] = {};

#define ISSUEQ(j)                                                        \
  do {                                                                   \
    char* _r = ldsb + ((j) % 3) * 16384;                                 \
    const int _kb = (j) * 64;                                            \
    _Pragma("unroll")                                                    \
    for (int q = 0; q < 2; ++q) {                                        \
      gload16(gHb + aOff[q] + _kb, _r + aP[q]);                          \
      gload16(gGb + bOff[q] + _kb, _r + bP[q]);                          \
    }                                                                    \
  } while (0)

  ISSUEQ(0); ISSUEQ(1);                         // 2-deep prefetch

  for (int j = 0; j < 14; ++j) {
    if (j < 13) { VMCNT4(); }                   // retire quantum j only
    else        { VMCNT0(); }                   // tail: last quantum
    BARRIER();                                  // all threads' quantum j landed
    if (j + 2 < 14) ISSUEQ(j + 2);              // into region just freed

    char* reg = ldsb + (j % 3) * 16384;
    bf16x8 a[4], b[4];
    #pragma unroll
    for (int f = 0; f < 4; ++f) {
      a[f] = *(const bf16x8*)(reg + aro[f]);
      b[f] = *(const bf16x8*)(reg + 8192 + bro[f]);
    }
    #pragma unroll
    for (int rf = 0; rf < 4; ++rf)
      #pragma unroll
      for (int cf = 0; cf < 4; ++cf)
        acc[rf][cf] = __builtin_amdgcn_mfma_f32_16x16x32_bf16(a[rf], b[cf], acc[rf][cf], 0, 0, 0);
  }
#undef ISSUEQ

  const int r4 = (lane >> 4) * 4, cc = lane & 15;
  const int rbase = tm + wm * 64 + r4;
  const int cbase = tn + wn * 64 + cc;
  #pragma unroll
  for (int rf = 0; rf < 4; ++rf)
    #pragma unroll
    for (int cf = 0; cf < 4; ++cf) {
      const int col = cbase + cf * 16;
      if (col < NBC) {
        #pragma unroll
        for (int rr = 0; rr < 4; ++rr)
          out[(size_t)(rbase + rf * 16 + rr) * NBC + col] = acc[rf][cf][rr];
      }
    }
}

extern "C" void kernel_launch(void* const* d_in, const int* in_sizes, int n_in,
                              void* d_out, int out_size, void* d_ws, size_t ws_size,
                              hipStream_t stream) {
  const float* word  = (const float*)d_in[0];
  const float* tag   = (const float*)d_in[1];
  const float* Tm    = (const float*)d_in[2];
  const float* Um    = (const float*)d_in[3];
  const float* Vm    = (const float*)d_in[4];
  const float* Wm    = (const float*)d_in[5];
  const float* first = (const float*)d_in[6];
  float* out = (float*)d_out;
  char* ws = (char*)d_ws;

  u16*   Wbf = (u16*)(ws + OFF_WBF);
  u16*   Ubt = (u16*)(ws + OFF_UBT);
  u16*   Tbt = (u16*)(ws + OFF_TBT);
  u16*   G   = (u16*)(ws + OFF_G);
  u16*   H   = (u16*)(ws + OFF_H);

  hipLaunchKernelGGL(prep_all, dim3(2048), dim3(256), 0, stream,
                     word, first, Um, Tm, tag, Vm, Wm, Wbf, Ubt, Tbt, G);
  hipLaunchKernelGGL(gemm_h,   dim3(128 * 4), dim3(256), 0, stream, Wbf, Ubt, Tbt, H);
  hipLaunchKernelGGL(gemm_big4, dim3(2560), dim3(256), 0, stream, H, G, out);
}

// Round 12
// 110.158 us; speedup vs baseline: 1.4828x; 1.1167x over previous
//
#include <hip/hip_runtime.h>

typedef unsigned short u16;
typedef __bf16 bf16x8 __attribute__((ext_vector_type(8)));
typedef float f32x4 __attribute__((ext_vector_type(4)));

#define WEMD 400
#define RANK 396
#define NA   16384     // SEQ*BATCH
#define KP   416       // padded wemd (400->416) for gemm_h K
#define K2   448       // padded rank (396->448) for gemm_big K (7 tiles of 64)
#define BSTR 896       // byte stride of H and G rows (448*2)
#define NBC  2500
#define NBCP 2560

// ---- ws layout (bytes) ----
#define OFF_WBF  0u                 // u16 [16416][416]
#define OFF_UBT  13658112u          // u16 [512][416]
#define OFF_TBT  14084096u          // u16 [512][416]
#define OFF_G    14689280u          // u16 [2560][448]
#define OFF_H    16983040u          // u16 [16384][448]

__device__ __forceinline__ u16 f2bf(float f) {
  union { float f; unsigned u; } v; v.f = f;
  unsigned u = v.u;
  return (u16)((u + 0x7FFFu + ((u >> 16) & 1u)) >> 16);  // RNE
}

typedef __attribute__((address_space(3))) unsigned char lds_byte;
typedef __attribute__((address_space(1))) const unsigned char glob_byte;

__device__ __forceinline__ void gload16(const void* g, void* l) {
  __builtin_amdgcn_global_load_lds((glob_byte*)g, (lds_byte*)l, 16, 0, 0);
}

// ---------- fused prep: Wbf + Ubt/Tbt + G (R4-proven, verbatim) ----------
__global__ __launch_bounds__(256) void prep_all(
    const float* __restrict__ word, const float* __restrict__ first,
    const float* __restrict__ U, const float* __restrict__ T,
    const float* __restrict__ tag, const float* __restrict__ V,
    const float* __restrict__ W,
    u16* __restrict__ Wbf, u16* __restrict__ Ubt, u16* __restrict__ Tbt,
    u16* __restrict__ G) {
  const int R0 = 16416 * 104;          // Wbf as float4 items (416/4 = 104 per row)
  const int R1 = 416 << 9;             // U/T transpose
  const int R2 = NBCP * K2;            // G items
  const int total = R0 + R1 + R2;
  for (int i = blockIdx.x * 256 + threadIdx.x; i < total; i += gridDim.x * 256) {
    if (i < R0) {
      int r = i / 104, c4 = i - r * 104;
      ushort4 o = {0, 0, 0, 0};
      if (c4 < 100) {
        const float* src = (r < 32) ? (first + c4 * 4)
                                    : (word + (size_t)(r - 32) * WEMD + c4 * 4);
        float4 v = *(const float4*)src;
        o.x = f2bf(v.x); o.y = f2bf(v.y); o.z = f2bf(v.z); o.w = f2bf(v.w);
      }
      *(ushort4*)(Wbf + (size_t)r * KP + c4 * 4) = o;
    } else if (i < R0 + R1) {
      int j = i - R0;
      int n = j & 511, k = j >> 9;
      u16 uo = 0, to = 0;
      if (n < RANK && k < WEMD) {
        uo = f2bf(U[(size_t)k * RANK + n]);
        to = f2bf(T[(size_t)k * RANK + n]);
      }
      Ubt[(size_t)n * KP + k] = uo;
      Tbt[(size_t)n * KP + k] = to;
    } else {
      int j = i - R0 - R1;
      int bc = j / K2, k = j - bc * K2;
      u16 g = 0;
      if (bc < NBC && k < RANK) {
        int b = bc / 50, c = bc - b * 50;
        float a2 = 0.f, a3 = 0.f;
        #pragma unroll
        for (int e = 0; e < 20; ++e) {
          a2 += tag[b * 20 + e] * V[e * RANK + k];
          a3 += tag[c * 20 + e] * W[e * RANK + k];
        }
        g = f2bf(a2 * a3);
      }
      G[(size_t)bc * K2 + k] = g;
    }
  }
}

// ---------- H = (word@U) * (neighbor@T), bf16 out, stride 448 ----------
// R4-proven structure verbatim; ONLY change: bijective XCD swizzle on the
// 512-block grid (pure index permutation, cannot affect correctness).
__global__ __launch_bounds__(256) void gemm_h(const u16* __restrict__ Wbf,
                                              const u16* __restrict__ Ubt,
                                              const u16* __restrict__ Tbt,
                                              u16* __restrict__ H) {
  __shared__ u16 As0[128 * 32], As1[128 * 32], Bu[128 * 32], Bt[128 * 32];
  const int tid = threadIdx.x;
  const int l = tid & 63, w = tid >> 6;
  const int wm = w >> 1, wn = w & 1;
  int bs = (int)blockIdx.x;
  bs = (bs & 7) * 64 + (bs >> 3);               // XCD swizzle, 512 % 8 == 0
  const int tm = (bs >> 2) * 128, tn = (bs & 3) * 128;

  f32x4 acc0[4][4] = {}, acc1[4][4] = {};

  const int srow = tid >> 2;
  const int scolb = (tid & 3) * 16;
  const char* gA0 = (const char*)Wbf + (size_t)(tm + 32 + srow) * 832 + scolb;
  const char* gA1 = (const char*)Wbf + (size_t)(tm + srow) * 832 + scolb;
  const char* gU  = (const char*)Ubt + (size_t)(tn + srow) * 832 + scolb;
  const char* gT  = (const char*)Tbt + (size_t)(tn + srow) * 832 + scolb;
  char* lA0 = (char*)As0 + tid * 16;
  char* lA1 = (char*)As1 + tid * 16;
  char* lU  = (char*)Bu  + tid * 16;
  char* lT  = (char*)Bt  + tid * 16;

  const int fo_a = (wm * 64 + (l & 15)) * 32 + (l >> 4) * 8;
  const int fo_b = (wn * 64 + (l & 15)) * 32 + (l >> 4) * 8;

  for (int kt = 0; kt < 13; ++kt) {
    const int kb = kt * 64;
    gload16(gA0 + kb, lA0); gload16(gA0 + kb + (size_t)64 * 832, lA0 + 4096);
    gload16(gA1 + kb, lA1); gload16(gA1 + kb + (size_t)64 * 832, lA1 + 4096);
    gload16(gU  + kb, lU ); gload16(gU  + kb + (size_t)64 * 832, lU  + 4096);
    gload16(gT  + kb, lT ); gload16(gT  + kb + (size_t)64 * 832, lT  + 4096);
    __syncthreads();
    bf16x8 a0[4], a1[4], bu[4], bt[4];
    #pragma unroll
    for (int i = 0; i < 4; ++i) {
      a0[i] = *(const bf16x8*)(As0 + fo_a + i * 16 * 32);
      a1[i] = *(const bf16x8*)(As1 + fo_a + i * 16 * 32);
      bu[i] = *(const bf16x8*)(Bu  + fo_b + i * 16 * 32);
      bt[i] = *(const bf16x8*)(Bt  + fo_b + i * 16 * 32);
    }
    #pragma unroll
    for (int i = 0; i < 4; ++i)
      #pragma unroll
      for (int j = 0; j < 4; ++j) {
        acc0[i][j] = __builtin_amdgcn_mfma_f32_16x16x32_bf16(a0[i], bu[j], acc0[i][j], 0, 0, 0);
        acc1[i][j] = __builtin_amdgcn_mfma_f32_16x16x32_bf16(a1[i], bt[j], acc1[i][j], 0, 0, 0);
      }
    __syncthreads();
  }

  const int r4 = (l >> 4) * 4, cc = l & 15;
  #pragma unroll
  for (int i = 0; i < 4; ++i)
    #pragma unroll
    for (int j = 0; j < 4; ++j) {
      const int col = tn + wn * 64 + j * 16 + cc;
      if (col < K2) {
        #pragma unroll
        for (int r = 0; r < 4; ++r) {
          const int rowg = tm + wm * 64 + i * 16 + r4 + r;
          H[(size_t)rowg * K2 + col] = f2bf(acc0[i][j][r] * acc1[i][j][r]);
        }
      }
    }
}

// ---------- out[16384,2500] = H[.,448] @ G^T (R4-proven, verbatim) ----------
// 128x128 tile, BK=64, 256 thr (4 waves 2x2), single-buffered 32 KiB LDS ->
// 3 blocks/CU; co-residency provides the overlap (m114). Validated swizzle:
// physical = logical ^ ((row&7)<<4), both sides.
__global__ __launch_bounds__(256, 3) void gemm_big2(const u16* __restrict__ H,
                                                    const u16* __restrict__ G,
                                                    float* __restrict__ out) {
  __shared__ u16 lds[2 * 8192];   // A 16 KiB + B 16 KiB
  char* ldsb = (char*)lds;
  const int tid = threadIdx.x;
  const int lane = tid & 63, wid = tid >> 6;
  const int wm = wid >> 1, wn = wid & 1;

  int bs = (int)blockIdx.x;
  bs = (bs & 7) * 320 + (bs >> 3);              // XCD swizzle, 2560 % 8 == 0
  const int tm = (bs / 20) * 128, tn = (bs % 20) * 128;

  const char* gH = (const char*)H + (size_t)tm * BSTR;
  const char* gG = (const char*)G + (size_t)tn * BSTR;

  int sP[4], sR[4], sC[4];
  #pragma unroll
  for (int q = 0; q < 4; ++q) {
    int P = tid * 16 + q * 4096;
    int L = P ^ (((P >> 7) & 7) << 4);
    sP[q] = P; sR[q] = L >> 7; sC[q] = L & 127;
  }
  const int arow = (lane & 15) * 128;
  const int sw = (lane & 7) << 4;

  f32x4 acc[4][4] = {};

  for (int kt = 0; kt < 7; ++kt) {
    const int kb = kt * 128;
    #pragma unroll
    for (int q = 0; q < 4; ++q) {
      gload16(gH + (size_t)sR[q] * BSTR + kb + sC[q], ldsb + sP[q]);
      gload16(gG + (size_t)sR[q] * BSTR + kb + sC[q], ldsb + 16384 + sP[q]);
    }
    __syncthreads();
    #pragma unroll
    for (int ks = 0; ks < 2; ++ks) {
      const int csw = (ks * 64 + (lane >> 4) * 16) ^ sw;
      bf16x8 a[4], b[4];
      #pragma unroll
      for (int rf = 0; rf < 4; ++rf)
        a[rf] = *(const bf16x8*)(ldsb + wm * 8192 + rf * 2048 + arow + csw);
      #pragma unroll
      for (int cf = 0; cf < 4; ++cf)
        b[cf] = *(const bf16x8*)(ldsb + 16384 + wn * 8192 + cf * 2048 + arow + csw);
      #pragma unroll
      for (int rf = 0; rf < 4; ++rf)
        #pragma unroll
        for (int cf = 0; cf < 4; ++cf)
          acc[rf][cf] = __builtin_amdgcn_mfma_f32_16x16x32_bf16(a[rf], b[cf], acc[rf][cf], 0, 0, 0);
    }
    __syncthreads();
  }

  const int r4 = (lane >> 4) * 4, cc = lane & 15;
  const int rbase = tm + wm * 64 + r4;
  const int cbase = tn + wn * 64 + cc;
  #pragma unroll
  for (int rf = 0; rf < 4; ++rf)
    #pragma unroll
    for (int cf = 0; cf < 4; ++cf) {
      const int col = cbase + cf * 16;
      if (col < NBC) {
        #pragma unroll
        for (int rr = 0; rr < 4; ++rr)
          out[(size_t)(rbase + rf * 16 + rr) * NBC + col] = acc[rf][cf][rr];
      }
    }
}

extern "C" void kernel_launch(void* const* d_in, const int* in_sizes, int n_in,
                              void* d_out, int out_size, void* d_ws, size_t ws_size,
                              hipStream_t stream) {
  const float* word  = (const float*)d_in[0];
  const float* tag   = (const float*)d_in[1];
  const float* Tm    = (const float*)d_in[2];
  const float* Um    = (const float*)d_in[3];
  const float* Vm    = (const float*)d_in[4];
  const float* Wm    = (const float*)d_in[5];
  const float* first = (const float*)d_in[6];
  float* out = (float*)d_out;
  char* ws = (char*)d_ws;

  u16*   Wbf = (u16*)(ws + OFF_WBF);
  u16*   Ubt = (u16*)(ws + OFF_UBT);
  u16*   Tbt = (u16*)(ws + OFF_TBT);
  u16*   G   = (u16*)(ws + OFF_G);
  u16*   H   = (u16*)(ws + OFF_H);

  hipLaunchKernelGGL(prep_all, dim3(2048), dim3(256), 0, stream,
                     word, first, Um, Tm, tag, Vm, Wm, Wbf, Ubt, Tbt, G);
  hipLaunchKernelGGL(gemm_h,   dim3(512), dim3(256), 0, stream, Wbf, Ubt, Tbt, H);
  hipLaunchKernelGGL(gemm_big2, dim3(2560), dim3(256), 0, stream, H, G, out);
}

// Round 13
// 105.528 us; speedup vs baseline: 1.5479x; 1.0439x over previous
//
#include <hip/hip_runtime.h>

typedef unsigned short u16;
typedef __bf16 bf16x8 __attribute__((ext_vector_type(8)));
typedef float f32x4 __attribute__((ext_vector_type(4)));

#define WEMD 400
#define RANK 396
#define NA   16384     // SEQ*BATCH
#define KP   416       // padded wemd (400->416) for gemm_h K
#define K2   448       // padded rank (396->448) for gemm_big K (7 tiles of 64)
#define BSTR 896       // byte stride of H and G rows (448*2)
#define NBC  2500
#define NBCP 2560

// ---- ws layout (bytes) ----
#define OFF_WBF  0u                 // u16 [16416][416]
#define OFF_UBT  13658112u          // u16 [512][416]
#define OFF_TBT  14084096u          // u16 [512][416]
#define OFF_G    14689280u          // u16 [2560][448]
#define OFF_H    16983040u          // u16 [16384][448]

__device__ __forceinline__ u16 f2bf(float f) {
  union { float f; unsigned u; } v; v.f = f;
  unsigned u = v.u;
  return (u16)((u + 0x7FFFu + ((u >> 16) & 1u)) >> 16);  // RNE
}

typedef __attribute__((address_space(3))) unsigned char lds_byte;
typedef __attribute__((address_space(1))) const unsigned char glob_byte;

__device__ __forceinline__ void gload16(const void* g, void* l) {
  __builtin_amdgcn_global_load_lds((glob_byte*)g, (lds_byte*)l, 16, 0, 0);
}

// ---------- fused prep: Wbf + Ubt/Tbt + G (R4-proven, verbatim) ----------
__global__ __launch_bounds__(256) void prep_all(
    const float* __restrict__ word, const float* __restrict__ first,
    const float* __restrict__ U, const float* __restrict__ T,
    const float* __restrict__ tag, const float* __restrict__ V,
    const float* __restrict__ W,
    u16* __restrict__ Wbf, u16* __restrict__ Ubt, u16* __restrict__ Tbt,
    u16* __restrict__ G) {
  const int R0 = 16416 * 104;          // Wbf as float4 items (416/4 = 104 per row)
  const int R1 = 416 << 9;             // U/T transpose
  const int R2 = NBCP * K2;            // G items
  const int total = R0 + R1 + R2;
  for (int i = blockIdx.x * 256 + threadIdx.x; i < total; i += gridDim.x * 256) {
    if (i < R0) {
      int r = i / 104, c4 = i - r * 104;
      ushort4 o = {0, 0, 0, 0};
      if (c4 < 100) {
        const float* src = (r < 32) ? (first + c4 * 4)
                                    : (word + (size_t)(r - 32) * WEMD + c4 * 4);
        float4 v = *(const float4*)src;
        o.x = f2bf(v.x); o.y = f2bf(v.y); o.z = f2bf(v.z); o.w = f2bf(v.w);
      }
      *(ushort4*)(Wbf + (size_t)r * KP + c4 * 4) = o;
    } else if (i < R0 + R1) {
      int j = i - R0;
      int n = j & 511, k = j >> 9;
      u16 uo = 0, to = 0;
      if (n < RANK && k < WEMD) {
        uo = f2bf(U[(size_t)k * RANK + n]);
        to = f2bf(T[(size_t)k * RANK + n]);
      }
      Ubt[(size_t)n * KP + k] = uo;
      Tbt[(size_t)n * KP + k] = to;
    } else {
      int j = i - R0 - R1;
      int bc = j / K2, k = j - bc * K2;
      u16 g = 0;
      if (bc < NBC && k < RANK) {
        int b = bc / 50, c = bc - b * 50;
        float a2 = 0.f, a3 = 0.f;
        #pragma unroll
        for (int e = 0; e < 20; ++e) {
          a2 += tag[b * 20 + e] * V[e * RANK + k];
          a3 += tag[c * 20 + e] * W[e * RANK + k];
        }
        g = f2bf(a2 * a3);
      }
      G[(size_t)bc * K2 + k] = g;
    }
  }
}

// ---------- H = (word@U) * (neighbor@T), bf16 out, stride 448 ----------
// Shared-A staging (solo re-land; R11 bundled it with the launch-bounds spill
// suspect): A0 (word rows = Wbf[tm+32..tm+160)) and A1 (neighbor rows =
// Wbf[tm..tm+128)) overlap by 96 rows -> stage Wbf rows [tm, tm+160) ONCE per
// kt (10 KB vs 16 KB, -19% staged bytes; LDS 26.6 KB -> more co-residency).
// A1 fragment at Ash row r; A0 at row r+32 (+1024 u16). XCD swizzle from R12.
__global__ __launch_bounds__(256) void gemm_h(const u16* __restrict__ Wbf,
                                              const u16* __restrict__ Ubt,
                                              const u16* __restrict__ Tbt,
                                              u16* __restrict__ H) {
  __shared__ __align__(16) u16 Ash[160 * 32];   // 10240 B
  __shared__ __align__(16) u16 Bu[128 * 32];    // 8192 B
  __shared__ __align__(16) u16 Bt[128 * 32];    // 8192 B
  const int tid = threadIdx.x;
  const int l = tid & 63, w = tid >> 6;
  const int wm = w >> 1, wn = w & 1;
  int bs = (int)blockIdx.x;
  bs = (bs & 7) * 64 + (bs >> 3);               // XCD swizzle, 512 % 8 == 0
  const int tm = (bs >> 2) * 128, tn = (bs & 3) * 128;

  f32x4 acc0[4][4] = {}, acc1[4][4] = {};

  const char* gA = (const char*)Wbf + (size_t)tm * 832;
  const char* gU = (const char*)Ubt + (size_t)tn * 832;
  const char* gT = (const char*)Tbt + (size_t)tn * 832;

  const int fo_a = (wm * 64 + (l & 15)) * 32 + (l >> 4) * 8;   // u16 units
  const int fo_b = (wn * 64 + (l & 15)) * 32 + (l >> 4) * 8;

  for (int kt = 0; kt < 13; ++kt) {
    const int kb = kt * 64;
    // A: rows [tm, tm+160), 64 B per row-chunk: q=0,1 all threads; q=2 tid<128
    #pragma unroll
    for (int q = 0; q < 2; ++q) {
      int P = tid * 16 + q * 4096;
      gload16(gA + (size_t)(P >> 6) * 832 + kb + (P & 63), (char*)Ash + P);
    }
    if (tid < 128) {
      int P = tid * 16 + 8192;
      gload16(gA + (size_t)(P >> 6) * 832 + kb + (P & 63), (char*)Ash + P);
    }
    #pragma unroll
    for (int q = 0; q < 2; ++q) {
      int P = tid * 16 + q * 4096;
      gload16(gU + (size_t)(P >> 6) * 832 + kb + (P & 63), (char*)Bu + P);
      gload16(gT + (size_t)(P >> 6) * 832 + kb + (P & 63), (char*)Bt + P);
    }
    __syncthreads();
    bf16x8 a0[4], a1[4], bu[4], bt[4];
    #pragma unroll
    for (int i = 0; i < 4; ++i) {
      a1[i] = *(const bf16x8*)(Ash + fo_a + i * 512);          // neighbor rows
      a0[i] = *(const bf16x8*)(Ash + fo_a + 1024 + i * 512);   // word rows (+32)
      bu[i] = *(const bf16x8*)(Bu  + fo_b + i * 512);
      bt[i] = *(const bf16x8*)(Bt  + fo_b + i * 512);
    }
    #pragma unroll
    for (int i = 0; i < 4; ++i)
      #pragma unroll
      for (int j = 0; j < 4; ++j) {
        acc0[i][j] = __builtin_amdgcn_mfma_f32_16x16x32_bf16(a0[i], bu[j], acc0[i][j], 0, 0, 0);
        acc1[i][j] = __builtin_amdgcn_mfma_f32_16x16x32_bf16(a1[i], bt[j], acc1[i][j], 0, 0, 0);
      }
    __syncthreads();
  }

  const int r4 = (l >> 4) * 4, cc = l & 15;
  #pragma unroll
  for (int i = 0; i < 4; ++i)
    #pragma unroll
    for (int j = 0; j < 4; ++j) {
      const int col = tn + wn * 64 + j * 16 + cc;
      if (col < K2) {
        #pragma unroll
        for (int r = 0; r < 4; ++r) {
          const int rowg = tm + wm * 64 + i * 16 + r4 + r;
          H[(size_t)rowg * K2 + col] = f2bf(acc0[i][j][r] * acc1[i][j][r]);
        }
      }
    }
}

// ---------- out[16384,2500] = H[.,448] @ G^T (R4-proven, verbatim) ----------
// 128x128 tile, BK=64, 256 thr (4 waves 2x2), single-buffered 32 KiB LDS ->
// 3 blocks/CU; co-residency provides the overlap (m114). Validated swizzle:
// physical = logical ^ ((row&7)<<4), both sides.
// NOTE: __launch_bounds__(256,4) retired permanently — R11 showed replay-only
// divergence consistent with spill-scratch corruption under graph capture.
__global__ __launch_bounds__(256, 3) void gemm_big2(const u16* __restrict__ H,
                                                    const u16* __restrict__ G,
                                                    float* __restrict__ out) {
  __shared__ u16 lds[2 * 8192];   // A 16 KiB + B 16 KiB
  char* ldsb = (char*)lds;
  const int tid = threadIdx.x;
  const int lane = tid & 63, wid = tid >> 6;
  const int wm = wid >> 1, wn = wid & 1;

  int bs = (int)blockIdx.x;
  bs = (bs & 7) * 320 + (bs >> 3);              // XCD swizzle, 2560 % 8 == 0
  const int tm = (bs / 20) * 128, tn = (bs % 20) * 128;

  const char* gH = (const char*)H + (size_t)tm * BSTR;
  const char* gG = (const char*)G + (size_t)tn * BSTR;

  int sP[4], sR[4], sC[4];
  #pragma unroll
  for (int q = 0; q < 4; ++q) {
    int P = tid * 16 + q * 4096;
    int L = P ^ (((P >> 7) & 7) << 4);
    sP[q] = P; sR[q] = L >> 7; sC[q] = L & 127;
  }
  const int arow = (lane & 15) * 128;
  const int sw = (lane & 7) << 4;

  f32x4 acc[4][4] = {};

  for (int kt = 0; kt < 7; ++kt) {
    const int kb = kt * 128;
    #pragma unroll
    for (int q = 0; q < 4; ++q) {
      gload16(gH + (size_t)sR[q] * BSTR + kb + sC[q], ldsb + sP[q]);
      gload16(gG + (size_t)sR[q] * BSTR + kb + sC[q], ldsb + 16384 + sP[q]);
    }
    __syncthreads();
    #pragma unroll
    for (int ks = 0; ks < 2; ++ks) {
      const int csw = (ks * 64 + (lane >> 4) * 16) ^ sw;
      bf16x8 a[4], b[4];
      #pragma unroll
      for (int rf = 0; rf < 4; ++rf)
        a[rf] = *(const bf16x8*)(ldsb + wm * 8192 + rf * 2048 + arow + csw);
      #pragma unroll
      for (int cf = 0; cf < 4; ++cf)
        b[cf] = *(const bf16x8*)(ldsb + 16384 + wn * 8192 + cf * 2048 + arow + csw);
      #pragma unroll
      for (int rf = 0; rf < 4; ++rf)
        #pragma unroll
        for (int cf = 0; cf < 4; ++cf)
          acc[rf][cf] = __builtin_amdgcn_mfma_f32_16x16x32_bf16(a[rf], b[cf], acc[rf][cf], 0, 0, 0);
    }
    __syncthreads();
  }

  const int r4 = (lane >> 4) * 4, cc = lane & 15;
  const int rbase = tm + wm * 64 + r4;
  const int cbase = tn + wn * 64 + cc;
  #pragma unroll
  for (int rf = 0; rf < 4; ++rf)
    #pragma unroll
    for (int cf = 0; cf < 4; ++cf) {
      const int col = cbase + cf * 16;
      if (col < NBC) {
        #pragma unroll
        for (int rr = 0; rr < 4; ++rr)
          out[(size_t)(rbase + rf * 16 + rr) * NBC + col] = acc[rf][cf][rr];
      }
    }
}

extern "C" void kernel_launch(void* const* d_in, const int* in_sizes, int n_in,
                              void* d_out, int out_size, void* d_ws, size_t ws_size,
                              hipStream_t stream) {
  const float* word  = (const float*)d_in[0];
  const float* tag   = (const float*)d_in[1];
  const float* Tm    = (const float*)d_in[2];
  const float* Um    = (const float*)d_in[3];
  const float* Vm    = (const float*)d_in[4];
  const float* Wm    = (const float*)d_in[5];
  const float* first = (const float*)d_in[6];
  float* out = (float*)d_out;
  char* ws = (char*)d_ws;

  u16*   Wbf = (u16*)(ws + OFF_WBF);
  u16*   Ubt = (u16*)(ws + OFF_UBT);
  u16*   Tbt = (u16*)(ws + OFF_TBT);
  u16*   G   = (u16*)(ws + OFF_G);
  u16*   H   = (u16*)(ws + OFF_H);

  hipLaunchKernelGGL(prep_all, dim3(2048), dim3(256), 0, stream,
                     word, first, Um, Tm, tag, Vm, Wm, Wbf, Ubt, Tbt, G);
  hipLaunchKernelGGL(gemm_h,   dim3(512), dim3(256), 0, stream, Wbf, Ubt, Tbt, H);
  hipLaunchKernelGGL(gemm_big2, dim3(2560), dim3(256), 0, stream, H, G, out);
}